// Round 10
// baseline (71.686 us; speedup 1.0000x reference)
//
#include <hip/hip_runtime.h>
#include <math.h>

#define N_FFT 16384
#define HALF 8192
#define ROWS 1024    // B*Cin = B*Cout = 16*64
#define KS_A 64      // k-splits of the 8192 half-space
#define KR_A 128     // half-k per kA block
#define CHUNK 64     // half-k per LDS stage (2 chunks per block)
#define NMASK 16383

typedef float float4n __attribute__((ext_vector_type(4)));

// ---------------- ws layout (float offsets) ----------------
// castab @0      [16384]   cas(2*pi*i/N)
// costab @16384  [16384]   2*cos(2*pi*i/N)
// partial@32768  [64*65536]
// xh     @4227072 [65536]
// lowT   @4292608 [65536]

__global__ __launch_bounds__(256) void k_tab(float* __restrict__ castab,
                                             float* __restrict__ costab) {
    int i = blockIdx.x * 256 + threadIdx.x;   // grid 64*256 = 16384 exactly
    double ang = 6.283185307179586476925287 * (double)i / (double)N_FFT;
    double c = cos(ang), s = sin(ang);
    castab[i] = (float)(c + s);
    costab[i] = (float)(2.0 * c);
}

// Step A (half-symmetric + cas recurrence):
//   partial[ks][r][c] = sum_{k in split} (x[r][k] +- x[r][k+8192]) * cas(k*m_c*theta)
// grid 512 = 8 rb * 64 ks; block 512 = 8 waves; wave = 8 m-cols (single parity),
// lane = 2 rows. T14 staging: next chunk's global loads issued before compute.
// LDS writes swizzled rsw = r ^ (kq<<2); reads use matching swizzle.
__global__ __launch_bounds__(512, 4) void kA(const float* __restrict__ x,
                                             const float* __restrict__ castab,
                                             const float* __restrict__ costab,
                                             float* __restrict__ partial) {
    const int rb = blockIdx.x & 7;
    const int ks = blockIdx.x >> 3;
    const int rowbase = rb << 7;
    const int kbase = ks * KR_A;

    __shared__ float xs[CHUNK][2][128];   // [k][parity][row-swizzled], 64 KB

    const int t   = threadIdx.x;
    const int wq  = __builtin_amdgcn_readfirstlane(t >> 6);  // 0..7, uniform
    const int lam = t & 63;
    const int c0  = wq * 8;               // permuted col octet (single parity)
    const int p   = wq >> 2;              // 0: even m (sum), 1: odd m (diff)
    const int r2  = lam * 2;              // local row pair
    const int mbase = (wq < 4) ? (wq << 4) : (((wq - 4) << 4) + 1);

    float k2[8], cA[8], cB[8];
#pragma unroll
    for (int j = 0; j < 8; ++j) {
        const int m = mbase + 2 * j;
        k2[j] = costab[m];                              // 2*cos(m*theta)
        cB[j] = castab[((kbase - 1) * m) & NMASK];      // cas((kbase-1)*m)
        cA[j] = castab[(kbase * m) & NMASK];            // cas(kbase*m)
    }

    float acc0[8], acc1[8];
#pragma unroll
    for (int j = 0; j < 8; ++j) { acc0[j] = 0.f; acc1[j] = 0.f; }

    float4n xa[4], xb[4];   // reg-staged tile (T14)

#define LOADCH(K0)                                                            \
    _Pragma("unroll")                                                         \
    for (int it = 0; it < 4; ++it) {                                          \
        const int idx = it * 512 + t;                                         \
        const int r = idx >> 4, kq = idx & 15;                                \
        const float* src = &x[(size_t)(rowbase + r) * N_FFT + (K0) + kq * 4]; \
        xa[it] = __builtin_nontemporal_load(                                  \
            reinterpret_cast<const float4n*>(src));                           \
        xb[it] = __builtin_nontemporal_load(                                  \
            reinterpret_cast<const float4n*>(src + HALF));                    \
    }

#define WRITECH()                                                             \
    _Pragma("unroll")                                                         \
    for (int it = 0; it < 4; ++it) {                                          \
        const int idx = it * 512 + t;                                         \
        const int r = idx >> 4, kq = idx & 15;                                \
        const int rsw = r ^ (kq << 2);                                        \
        _Pragma("unroll")                                                     \
        for (int u = 0; u < 4; ++u) {                                         \
            const float a = xa[it][u];                                        \
            const float b = xb[it][u];                                        \
            xs[kq * 4 + u][0][rsw] = a + b;                                   \
            xs[kq * 4 + u][1][rsw] = a - b;                                   \
        }                                                                     \
    }

    LOADCH(kbase);
    for (int ch = 0; ch < 2; ++ch) {
        if (ch) __syncthreads();          // prev compute done, LDS free
        WRITECH();
        __syncthreads();
        if (ch == 0) { LOADCH(kbase + CHUNK); }   // in flight during compute
#pragma unroll 4
        for (int k = 0; k < CHUNK; k += 2) {
            const int rd = r2 ^ ((k >> 2) << 2);   // same for k and k+1
            {   // step k: current = cA; then cB <- c_{k+1}
                const float2 s2 = *reinterpret_cast<const float2*>(&xs[k][p][rd]);
#pragma unroll
                for (int j = 0; j < 8; ++j) {
                    acc0[j] = fmaf(s2.x, cA[j], acc0[j]);
                    acc1[j] = fmaf(s2.y, cA[j], acc1[j]);
                    cB[j] = fmaf(k2[j], cA[j], -cB[j]);
                }
            }
            {   // step k+1: current = cB; then cA <- c_{k+2}
                const float2 s2 = *reinterpret_cast<const float2*>(&xs[k + 1][p][rd]);
#pragma unroll
                for (int j = 0; j < 8; ++j) {
                    acc0[j] = fmaf(s2.x, cB[j], acc0[j]);
                    acc1[j] = fmaf(s2.y, cB[j], acc1[j]);
                    cA[j] = fmaf(k2[j], cB[j], -cA[j]);
                }
            }
        }
    }
#undef LOADCH
#undef WRITECH

#pragma unroll
    for (int i = 0; i < 2; ++i) {
        float* pp = &partial[((size_t)ks << 16) +
                             (size_t)(rowbase + r2 + i) * 64 + c0];
        const float* a = i ? acc1 : acc0;
        *reinterpret_cast<float4*>(pp) =
            make_float4(a[0], a[1], a[2], a[3]);
        *reinterpret_cast<float4*>(pp + 4) =
            make_float4(a[4], a[5], a[6], a[7]);
    }
}

// reduce KS_A partials -> xh (un-permuting columns)
// grid 1024 blocks x 256: block = 64 idx x 4 sp-groups; LDS reduce across groups.
__global__ __launch_bounds__(256) void kR(const float* __restrict__ partial,
                                          float* __restrict__ xh) {
    const int lane = threadIdx.x & 63;
    const int sg   = threadIdx.x >> 6;              // 0..3
    const int idx  = blockIdx.x * 64 + lane;        // 0..65535
    const int sp0  = sg << 4;

    float a0 = 0.f, a1 = 0.f, a2 = 0.f, a3 = 0.f;
#pragma unroll
    for (int i = 0; i < 16; i += 4) {
        a0 += partial[((size_t)(sp0 + i + 0) << 16) + idx];
        a1 += partial[((size_t)(sp0 + i + 1) << 16) + idx];
        a2 += partial[((size_t)(sp0 + i + 2) << 16) + idx];
        a3 += partial[((size_t)(sp0 + i + 3) << 16) + idx];
    }
    const float s = (a0 + a1) + (a2 + a3);

    __shared__ float red[4][64];
    red[sg][lane] = s;
    __syncthreads();
    if (sg == 0) {
        const float v = (red[0][lane] + red[1][lane]) +
                        (red[2][lane] + red[3][lane]);
        const int r = idx >> 6, c = idx & 63;
        const int m = (c < 32) ? (2 * c) : (2 * (c - 32) + 1);
        xh[(r << 6) + m] = v;
    }
}

// Step B: lowT[m][b*64+o] = (1/N) * sum_i xh[b*64+i][m] * w[(o*64+i)*64+m]
// grid 512 = 16 b * 32 o-pairs; block 256 = 2 ih * 2 oo * 64 m; LDS reduce over ih.
__global__ __launch_bounds__(256) void kB(const float* __restrict__ xh,
                                          const float* __restrict__ w,
                                          float* __restrict__ lowT) {
    const int b  = blockIdx.x >> 5;
    const int op = blockIdx.x & 31;
    const int m  = threadIdx.x & 63;
    const int oo = (threadIdx.x >> 6) & 1;
    const int ih = threadIdx.x >> 7;
    const int o  = op * 2 + oo;
    const int i0 = ih * 32;

    float a0 = 0.f, a1 = 0.f, a2 = 0.f, a3 = 0.f;
#pragma unroll
    for (int ii = 0; ii < 32; ii += 4) {
        const int i = i0 + ii;
        a0 = fmaf(xh[(size_t)((b * 64 + i + 0) << 6) + m], w[(size_t)((o * 64 + i + 0) << 6) + m], a0);
        a1 = fmaf(xh[(size_t)((b * 64 + i + 1) << 6) + m], w[(size_t)((o * 64 + i + 1) << 6) + m], a1);
        a2 = fmaf(xh[(size_t)((b * 64 + i + 2) << 6) + m], w[(size_t)((o * 64 + i + 2) << 6) + m], a2);
        a3 = fmaf(xh[(size_t)((b * 64 + i + 3) << 6) + m], w[(size_t)((o * 64 + i + 3) << 6) + m], a3);
    }
    const float s = (a0 + a1) + (a2 + a3);

    __shared__ float red[2][128];
    red[ih][oo * 64 + m] = s;
    __syncthreads();
    if (ih == 0) {
        lowT[(size_t)m * ROWS + b * 64 + o] =
            (s + red[1][oo * 64 + m]) * (1.0f / (float)N_FFT);
    }
}

// Step C (half-symmetric + cas recurrence):
//   out[r][n] = Se+So, out[r][n+8192] = Se-So (n<8192)
// grid 2048 = 16 rb * 128 nb; block 256 = 4 waves; wave = 16 rows (uniform ->
// lowT via s_load), lane = 1 n. Inner loop: zero vector memory ops.
__global__ __launch_bounds__(256, 4) void kC(const float* __restrict__ lowT,
                                             const float* __restrict__ castab,
                                             const float* __restrict__ costab,
                                             float* __restrict__ out) {
    const int nb = blockIdx.x & 127;
    const int rb = blockIdx.x >> 7;
    const int t  = threadIdx.x;
    const int wq = __builtin_amdgcn_readfirstlane(t >> 6);   // 0..3, uniform
    const int r0 = rb * 64 + wq * 16;                        // wave-uniform rows
    const int n  = (nb << 6) + (t & 63);                     // 0..8191

    const float k2 = costab[n];   // 2*cos(n*theta)
    float ce = 1.0f;              // cas(0)
    float co = castab[n];         // cas(n*theta)

    float se[16], so[16];
#pragma unroll
    for (int j = 0; j < 16; ++j) { se[j] = 0.f; so[j] = 0.f; }

#pragma unroll 4
    for (int g = 0; g < 32; ++g) {
        const float* le = lowT + ((size_t)(2 * g) << 10) + r0;   // uniform addr
        const float* lo = le + ROWS;
#pragma unroll
        for (int j = 0; j < 16; ++j) {
            se[j] = fmaf(ce, le[j], se[j]);
            so[j] = fmaf(co, lo[j], so[j]);
        }
        ce = fmaf(k2, co, -ce);   // cas((2g+2)*n)
        co = fmaf(k2, ce, -co);   // cas((2g+3)*n)
    }

#pragma unroll
    for (int j = 0; j < 16; ++j) {
        const size_t row = (size_t)r0 + j;
        __builtin_nontemporal_store(se[j] + so[j], &out[row * N_FFT + n]);
        __builtin_nontemporal_store(se[j] - so[j], &out[row * N_FFT + HALF + n]);
    }
}

extern "C" void kernel_launch(void* const* d_in, const int* in_sizes, int n_in,
                              void* d_out, int out_size, void* d_ws, size_t ws_size,
                              hipStream_t stream) {
    const float* x = (const float*)d_in[0];
    const float* w = (const float*)d_in[1];
    float* out = (float*)d_out;
    float* ws  = (float*)d_ws;

    float* castab  = ws;
    float* costab  = ws + 16384;
    float* partial = ws + 32768;
    float* xh      = ws + 4227072;
    float* lowT    = ws + 4292608;

    k_tab<<<64, 256, 0, stream>>>(castab, costab);
    kA<<<512, 512, 0, stream>>>(x, castab, costab, partial);
    kR<<<1024, 256, 0, stream>>>(partial, xh);
    kB<<<512, 256, 0, stream>>>(xh, w, lowT);
    kC<<<2048, 256, 0, stream>>>(lowT, castab, costab, out);
}